// Round 9
// baseline (433.772 us; speedup 1.0000x reference)
//
#include <hip/hip_runtime.h>
#include <math.h>

typedef __bf16 bf16x8 __attribute__((ext_vector_type(8)));
typedef float  f32x4  __attribute__((ext_vector_type(4)));
typedef unsigned short u16x8 __attribute__((ext_vector_type(8)));

#define NEGF (-1e20f)

__device__ __forceinline__ unsigned short f2bf(float f) {
  union { float f; unsigned u; } x; x.f = f;
  unsigned r = x.u + 0x7fffu + ((x.u >> 16) & 1u);
  return (unsigned short)(r >> 16);
}
__device__ __forceinline__ unsigned short f2bfh(float f) {
  __bf16 h = (__bf16)f;
  return __builtin_bit_cast(unsigned short, h);
}
__device__ __forceinline__ float bf2f(unsigned short h) {
  union { unsigned u; float f; } x; x.u = ((unsigned)h) << 16;
  return x.f;
}

__device__ __forceinline__ void gl16(const void* g, void* l) {
  __builtin_amdgcn_global_load_lds(
      (const __attribute__((address_space(1))) unsigned int*)g,
      (__attribute__((address_space(3))) unsigned int*)l, 16, 0, 0);
}
__device__ __forceinline__ unsigned lds_addr(const void* p) {
  return (unsigned)(unsigned long long)(const __attribute__((address_space(3))) char*)p;
}

#define DSR(dst, off) asm volatile("ds_read_b128 %0, %1" : "=v"(dst) : "v"(off))
#define LGKM0 asm volatile("s_waitcnt lgkmcnt(0)" ::: "memory")
#define VMC0  asm volatile("s_waitcnt vmcnt(0)" ::: "memory")
#define SBAR  __builtin_amdgcn_s_barrier()
#define SCH0  __builtin_amdgcn_sched_barrier(0)

// ---------------- f32 -> bf16 convert (hw cvt), 16 elems/thread -------
__global__ __launch_bounds__(256) void k_cvt3(
    const float* __restrict__ q, const float* __restrict__ k, const float* __restrict__ v,
    unsigned short* __restrict__ qo, unsigned short* __restrict__ ko, unsigned short* __restrict__ vo) {
  const float* in = (blockIdx.y == 0) ? q : (blockIdx.y == 1) ? k : v;
  unsigned short* out = (blockIdx.y == 0) ? qo : (blockIdx.y == 1) ? ko : vo;
  size_t i = ((size_t)blockIdx.x * 256 + threadIdx.x) * 16;
  const float4* p = (const float4*)(in + i);
  float4 a = p[0], b = p[1], c = p[2], d = p[3];
  u16x8 o0, o1;
  o0[0] = f2bfh(a.x); o0[1] = f2bfh(a.y); o0[2] = f2bfh(a.z); o0[3] = f2bfh(a.w);
  o0[4] = f2bfh(b.x); o0[5] = f2bfh(b.y); o0[6] = f2bfh(b.z); o0[7] = f2bfh(b.w);
  o1[0] = f2bfh(c.x); o1[1] = f2bfh(c.y); o1[2] = f2bfh(c.z); o1[3] = f2bfh(c.w);
  o1[4] = f2bfh(d.x); o1[5] = f2bfh(d.y); o1[6] = f2bfh(d.z); o1[7] = f2bfh(d.w);
  *(u16x8*)(out + i) = o0;
  *(u16x8*)(out + i + 8) = o1;
}

// ---------------- W (1024x1024 f32) -> W^T bf16, 3 weights ------------
__global__ __launch_bounds__(256) void k_cvt_w3(
    const float* __restrict__ Wq, const float* __restrict__ Wk, const float* __restrict__ Wv,
    unsigned short* __restrict__ Tq, unsigned short* __restrict__ Tk, unsigned short* __restrict__ Tv) {
  const float* W = (blockIdx.z == 0) ? Wq : (blockIdx.z == 1) ? Wk : Wv;
  unsigned short* WT = (blockIdx.z == 0) ? Tq : (blockIdx.z == 1) ? Tk : Tv;
  __shared__ float t[32][33];
  const int tid = threadIdx.x;
  const int tx = tid & 31, ty = tid >> 5;
  const int e0 = blockIdx.y * 32, a0 = blockIdx.x * 32;
#pragma unroll
  for (int i = 0; i < 4; i++) {
    int el = ty + i * 8;
    t[el][tx] = W[(size_t)(e0 + el) * 1024 + a0 + tx];
  }
  __syncthreads();
#pragma unroll
  for (int i = 0; i < 4; i++) {
    int al = ty + i * 8;
    WT[(size_t)(a0 + al) * 1024 + e0 + tx] = f2bf(t[tx][al]);
  }
}

// ---------------- mask int32 -> bits, 16 ints per thread --------------
__global__ __launch_bounds__(256) void k_maskbits(const int* __restrict__ mask,
                                                  unsigned short* __restrict__ bits) {
  size_t t = (size_t)blockIdx.x * 256 + threadIdx.x;
  const int4* p = (const int4*)(mask + t * 16);
  int4 a = p[0], b = p[1], c = p[2], d = p[3];
  unsigned m = 0;
  m |= (a.x != 0) ? 1u : 0u;      m |= (a.y != 0) ? 2u : 0u;
  m |= (a.z != 0) ? 4u : 0u;      m |= (a.w != 0) ? 8u : 0u;
  m |= (b.x != 0) ? 16u : 0u;     m |= (b.y != 0) ? 32u : 0u;
  m |= (b.z != 0) ? 64u : 0u;     m |= (b.w != 0) ? 128u : 0u;
  m |= (c.x != 0) ? 256u : 0u;    m |= (c.y != 0) ? 512u : 0u;
  m |= (c.z != 0) ? 1024u : 0u;   m |= (c.w != 0) ? 2048u : 0u;
  m |= (d.x != 0) ? 4096u : 0u;   m |= (d.y != 0) ? 8192u : 0u;
  m |= (d.z != 0) ? 16384u : 0u;  m |= (d.w != 0) ? 32768u : 0u;
  bits[t] = (unsigned short)m;
}

// =====================================================================
// shared 256x256 2-phase core (8 waves 2x4, BK=64 as 2 K-halves,
// gl16 both sides, chunk swizzle, one vmcnt(0)+barrier per K-tile).
// Proven at ~856 TF-equivalent as r7's k_proj256.
// =====================================================================
__device__ __forceinline__ void gemm256_core(
    const unsigned short* __restrict__ A, int lda,
    const unsigned short* __restrict__ Bt, int ldb,
    int brow, int bcol, int NT,
    unsigned short* As0, unsigned short* Bs0,
    f32x4 (&acc)[8][4])
{
  const int tid = threadIdx.x, w = tid >> 6, l = tid & 63;
  const int wr = w >> 2, wc = w & 3;
  const int fr = l & 15, fq = l >> 4;
  const int hr = l >> 3;
  const int hc = ((l & 7) ^ hr) * 8;

  const unsigned short* ga = A + (size_t)(brow + w * 32 + hr) * lda + hc;
  const unsigned short* gb = Bt + (size_t)(bcol + w * 32 + hr) * ldb + hc;

  unsigned aA[8], aB[4];
#pragma unroll
  for (int m = 0; m < 8; m++) aA[m] = lds_addr(As0) + (unsigned)((wr * 128 + m * 16 + fr) * 128);
#pragma unroll
  for (int n = 0; n < 4; n++) aB[n] = lds_addr(Bs0) + (unsigned)((wc * 64 + n * 16 + fr) * 128);
  const unsigned ck0 = (unsigned)((fq ^ (fr & 7)) * 16);
  const unsigned ck1 = (unsigned)(((4 + fq) ^ (fr & 7)) * 16);

  auto stage = [&](int buf, int k0) {
#pragma unroll
    for (int i = 0; i < 4; i++) {
      gl16(ga + (size_t)(8 * i) * lda + k0, As0 + buf * (256 * 64) + (w * 32 + 8 * i) * 64);
      gl16(gb + (size_t)(8 * i) * ldb + k0, Bs0 + buf * (256 * 64) + (w * 32 + 8 * i) * 64);
    }
  };

  stage(0, 0);
  VMC0; SBAR;
  for (int t = 0; t < NT; ++t) {
    if (t + 1 < NT) stage((t + 1) & 1, (t + 1) << 6);
    const unsigned bo = (unsigned)((t & 1) * (256 * 64 * 2));
    u16x8 ar[8], br[4];
#pragma unroll
    for (int m = 0; m < 8; m++) DSR(ar[m], aA[m] + bo + ck0);
#pragma unroll
    for (int n = 0; n < 4; n++) DSR(br[n], aB[n] + bo + ck0);
    LGKM0; SCH0;
    __builtin_amdgcn_s_setprio(1);
#pragma unroll
    for (int m = 0; m < 8; m++)
#pragma unroll
      for (int n = 0; n < 4; n++)
        acc[m][n] = __builtin_amdgcn_mfma_f32_16x16x32_bf16(
            __builtin_bit_cast(bf16x8, ar[m]), __builtin_bit_cast(bf16x8, br[n]), acc[m][n], 0, 0, 0);
    __builtin_amdgcn_s_setprio(0);
    u16x8 ar2[8], br2[4];
#pragma unroll
    for (int m = 0; m < 8; m++) DSR(ar2[m], aA[m] + bo + ck1);
#pragma unroll
    for (int n = 0; n < 4; n++) DSR(br2[n], aB[n] + bo + ck1);
    LGKM0; SCH0;
    __builtin_amdgcn_s_setprio(1);
#pragma unroll
    for (int m = 0; m < 8; m++)
#pragma unroll
      for (int n = 0; n < 4; n++)
        acc[m][n] = __builtin_amdgcn_mfma_f32_16x16x32_bf16(
            __builtin_bit_cast(bf16x8, ar2[m]), __builtin_bit_cast(bf16x8, br2[n]), acc[m][n], 0, 0, 0);
    __builtin_amdgcn_s_setprio(0);
    SCH0;
    VMC0; SBAR;
  }
}

// ---------------- projections (bf16 A via cvt3, W^T B) ----------------
__global__ __launch_bounds__(512, 2) void k_proj256(
    const unsigned short* __restrict__ A, int lda,
    const unsigned short* __restrict__ Bt, int ldb,
    unsigned short* __restrict__ C, int ldc, float scale)
{
  const int nwg = gridDim.x * gridDim.y;
  int lin = blockIdx.y * gridDim.x + blockIdx.x;
  int swz = (lin & 7) * (nwg >> 3) + (lin >> 3);   // nwg % 8 == 0
  const int bx = swz % gridDim.x, by = swz / gridDim.x;
  const int brow = by * 256, bcol = bx * 256;

  __shared__ unsigned short As[2][256 * 64];
  __shared__ unsigned short Bs[2][256 * 64];
  const int tid = threadIdx.x, w = tid >> 6, l = tid & 63;
  const int wr = w >> 2, wc = w & 3;
  const int fr = l & 15, fq = l >> 4;

  f32x4 acc[8][4] = {};
  gemm256_core(A, lda, Bt, ldb, brow, bcol, 16, &As[0][0], &Bs[0][0], acc);

#pragma unroll
  for (int m = 0; m < 8; m++)
#pragma unroll
    for (int n = 0; n < 4; n++)
#pragma unroll
      for (int r = 0; r < 4; r++) {
        int rg = brow + wr * 128 + m * 16 + fq * 4 + r;
        int cg = bcol + wc * 64 + n * 16 + fr;
        C[(size_t)rg * ldc + cg] = f2bf(acc[m][n][r] * scale);
      }
}

// ---------------- scores: 256-tile causal grid + packed mask ----------
__global__ __launch_bounds__(512, 2) void k_scores256(
    const unsigned short* __restrict__ QP,
    const unsigned short* __restrict__ KP,
    unsigned short* __restrict__ S,
    const unsigned short* __restrict__ maskbits)
{
  int bid = ((int)blockIdx.x & 7) * 36 + ((int)blockIdx.x >> 3);  // 288%8==0
  const int b = bid / 36;
  int t0 = bid - b * 36;
  int by = (int)((sqrtf((float)(8 * t0 + 1)) - 1.0f) * 0.5f);
  if ((by + 1) * (by + 2) / 2 <= t0) by++;
  else if (by * (by + 1) / 2 > t0) by--;
  const int bx = t0 - (by * (by + 1)) / 2;   // bx <= by
  const int brow = by * 256, bcol = bx * 256;

  const unsigned short* A  = QP + (size_t)b * (2048 * 1024);
  const unsigned short* Bt = KP + (size_t)b * (2048 * 1024);

  __shared__ unsigned short As[2][256 * 64];
  __shared__ unsigned short Bs[2][256 * 64];
  const int tid = threadIdx.x, w = tid >> 6, l = tid & 63;
  const int wr = w >> 2, wc = w & 3;
  const int fr = l & 15, fq = l >> 4;

  // mask bits prefetch: 128 epilogue elements per lane -> 4 u32
  const unsigned short* bits = maskbits + (size_t)b * 2048 * 128;
  unsigned mbits[4] = {0u, 0u, 0u, 0u};
#pragma unroll
  for (int m = 0; m < 8; m++)
#pragma unroll
    for (int r = 0; r < 4; r++) {
      int qq = brow + wr * 128 + m * 16 + fq * 4 + r;
      unsigned long long mw =
          *(const unsigned long long*)(bits + (size_t)qq * 128 + ((bcol + wc * 64) >> 4));
#pragma unroll
      for (int n = 0; n < 4; n++) {
        int jj = (m << 4) | (n << 2) | r;
        unsigned bit = (unsigned)((mw >> (n * 16 + fr)) & 1ull);
        mbits[jj >> 5] |= bit << (jj & 31);
      }
    }
  asm volatile("" ::: "memory");

  f32x4 acc[8][4] = {};
  gemm256_core(A, 1024, Bt, 1024, brow, bcol, 16, &As[0][0], &Bs[0][0], acc);

  unsigned short* Cb = S + (size_t)b * 2048 * 2048;
#pragma unroll
  for (int m = 0; m < 8; m++)
#pragma unroll
    for (int n = 0; n < 4; n++)
#pragma unroll
      for (int r = 0; r < 4; r++) {
        int jj = (m << 4) | (n << 2) | r;
        int qq = brow + wr * 128 + m * 16 + fq * 4 + r;
        int kk = bcol + wc * 64 + n * 16 + fr;
        float s = acc[m][n][r];
        if (!((mbits[jj >> 5] >> (jj & 31)) & 1u)) s = NEGF;
        if (kk > qq) s = NEGF;
        else if (s == 0.0f) s = NEGF;
        Cb[(size_t)qq * 2048 + kk] = f2bf(s);
      }
}

// ---------------- PV (f32 out, K truncated at diagonal) ---------------
__global__ __launch_bounds__(512, 2) void k_pv256(
    const unsigned short* __restrict__ P,
    const unsigned short* __restrict__ VpT,
    float* __restrict__ Out)
{
  const int b = blockIdx.z;
  const int by = (int)(gridDim.y - 1 - blockIdx.y);
  const int bx = blockIdx.x;
  const int brow = by * 256, bcol = bx * 256;

  const unsigned short* A  = P + (size_t)b * 2048 * 2048;
  const unsigned short* Bt = VpT + (size_t)b * 2048;

  __shared__ unsigned short As[2][256 * 64];
  __shared__ unsigned short Bs[2][256 * 64];
  const int tid = threadIdx.x, w = tid >> 6, l = tid & 63;
  const int wr = w >> 2, wc = w & 3;
  const int fr = l & 15, fq = l >> 4;

  f32x4 acc[8][4] = {};
  const int NT = (brow + 256) >> 6;
  gemm256_core(A, 2048, Bt, 16384, brow, bcol, NT, &As[0][0], &Bs[0][0], acc);

  float* C = Out + (size_t)b * 2048 * 1024;
#pragma unroll
  for (int m = 0; m < 8; m++)
#pragma unroll
    for (int n = 0; n < 4; n++)
#pragma unroll
      for (int r = 0; r < 4; r++) {
        int rg = brow + wr * 128 + m * 16 + fq * 4 + r;
        int cg = bcol + wc * 64 + n * 16 + fr;
        C[(size_t)rg * 1024 + cg] = acc[m][n][r];
      }
}

// ---------------- row softmax, bf16 in/out, 256-rounded ---------------
__global__ __launch_bounds__(256) void k_softmax_bf(unsigned short* __restrict__ S) {
  const int row = blockIdx.x;
  const int qq = row & 2047;
  const int L = ((qq >> 8) + 1) << 8;   // 256-tile-rounded row length
  const int tid = threadIdx.x;
  unsigned short* p = S + (size_t)row * 2048;
  float val[8];
  float mx = -3.0e38f;
  int cnt = 0;
  for (int i = tid; i * 4 < L; i += 256) {
    ushort4 u = *(const ushort4*)(p + i * 4);
    float a = bf2f(u.x), bb = bf2f(u.y), c = bf2f(u.z), d = bf2f(u.w);
    val[cnt] = a; val[cnt + 1] = bb; val[cnt + 2] = c; val[cnt + 3] = d;
    mx = fmaxf(fmaxf(fmaxf(mx, a), bb), fmaxf(c, d));
    cnt += 4;
  }
#pragma unroll
  for (int o = 32; o; o >>= 1) mx = fmaxf(mx, __shfl_xor(mx, o));
  __shared__ float sred[8];
  if ((tid & 63) == 0) sred[tid >> 6] = mx;
  __syncthreads();
  mx = fmaxf(fmaxf(sred[0], sred[1]), fmaxf(sred[2], sred[3]));
  float sum = 0.f;
  for (int j = 0; j < cnt; j++) { val[j] = __expf(val[j] - mx); sum += val[j]; }
#pragma unroll
  for (int o = 32; o; o >>= 1) sum += __shfl_xor(sum, o);
  if ((tid & 63) == 0) sred[4 + (tid >> 6)] = sum;
  __syncthreads();
  sum = (sred[4] + sred[5]) + (sred[6] + sred[7]);
  const float inv = 1.0f / sum;
  int j = 0;
  for (int i = tid; i * 4 < L; i += 256) {
    ushort4 o;
    o.x = f2bf(val[j] * inv);     o.y = f2bf(val[j + 1] * inv);
    o.z = f2bf(val[j + 2] * inv); o.w = f2bf(val[j + 3] * inv);
    *(ushort4*)(p + i * 4) = o;
    j += 4;
  }
}

extern "C" void kernel_launch(void* const* d_in, const int* in_sizes, int n_in,
                              void* d_out, int out_size, void* d_ws, size_t ws_size,
                              hipStream_t stream) {
  const float* q   = (const float*)d_in[0];
  const float* k   = (const float*)d_in[1];
  const float* v   = (const float*)d_in[2];
  const int*   msk = (const int*)d_in[3];
  const float* Wq  = (const float*)d_in[4];
  const float* Wk  = (const float*)d_in[5];
  const float* Wv  = (const float*)d_in[6];
  float* out = (float*)d_out;

  char* ws = (char*)d_ws;
  unsigned short* WqT = (unsigned short*)(ws + 0);
  unsigned short* WkT = (unsigned short*)(ws + 2097152);
  unsigned short* WvT = (unsigned short*)(ws + 4194304);
  unsigned short* qp  = (unsigned short*)(ws + 6291456);
  unsigned short* kp  = (unsigned short*)(ws + 39845888);
  unsigned short* vpT = (unsigned short*)(ws + 73400320);
  unsigned short* qbf = (unsigned short*)(ws + 106954752);
  unsigned short* kbf = (unsigned short*)(ws + 140509184);
  unsigned short* vbf = (unsigned short*)(ws + 174063616);
  // P (bf16 scores, 67 MB) aliases qbf/kbf/vbf (dead after projections)
  unsigned short* P = (unsigned short*)(ws + 106954752);
  unsigned short* mbitsbuf = (unsigned short*)(ws + 207618048);  // 4 MiB

  dim3 blk(256), blk5(512);
  // 1) conversions + mask packing
  k_cvt3<<<dim3(4096, 3), blk, 0, stream>>>(q, k, v, qbf, kbf, vbf);
  k_cvt_w3<<<dim3(32, 32, 3), blk, 0, stream>>>(Wq, Wk, Wv, WqT, WkT, WvT);
  k_maskbits<<<dim3(8192), blk, 0, stream>>>(msk, mbitsbuf);

  // 2) projections (256^2 2-phase): qp (1/32 folded), kp, vpT
  k_proj256<<<dim3(4, 64), blk5, 0, stream>>>(qbf, 1024, WqT, 1024, qp, 1024, 0.03125f);
  k_proj256<<<dim3(4, 64), blk5, 0, stream>>>(kbf, 1024, WkT, 1024, kp, 1024, 1.0f);
  k_proj256<<<dim3(64, 4), blk5, 0, stream>>>(WvT, 1024, vbf, 1024, vpT, 16384, 1.0f);

  // 3) scores (256-tile causal grid, bf16 out)
  k_scores256<<<dim3(288), blk5, 0, stream>>>(qp, kp, P, mbitsbuf);

  // 4) softmax in place (bf16, 256-rounded rows)
  k_softmax_bf<<<dim3(16384), blk, 0, stream>>>(P);

  // 5) PV: out = P x vpT^T, K truncated at diagonal
  k_pv256<<<dim3(4, 8, 8), blk5, 0, stream>>>(P, vpT, out);
  (void)in_sizes; (void)n_in; (void)out_size; (void)ws_size;
}

// Round 11
// 327.934 us; speedup vs baseline: 1.3227x; 1.3227x over previous
//
#include <hip/hip_runtime.h>
#include <math.h>

typedef __bf16 bf16x8 __attribute__((ext_vector_type(8)));
typedef float  f32x4  __attribute__((ext_vector_type(4)));
typedef unsigned short u16x8 __attribute__((ext_vector_type(8)));

#define NEGF (-1e20f)

__device__ __forceinline__ unsigned short f2bf(float f) {
  union { float f; unsigned u; } x; x.f = f;
  unsigned r = x.u + 0x7fffu + ((x.u >> 16) & 1u);
  return (unsigned short)(r >> 16);
}
__device__ __forceinline__ unsigned short f2bfh(float f) {
  __bf16 h = (__bf16)f;
  return __builtin_bit_cast(unsigned short, h);
}
__device__ __forceinline__ float bf2f(unsigned short h) {
  union { unsigned u; float f; } x; x.u = ((unsigned)h) << 16;
  return x.f;
}

__device__ __forceinline__ void gl16(const void* g, void* l) {
  __builtin_amdgcn_global_load_lds(
      (const __attribute__((address_space(1))) unsigned int*)g,
      (__attribute__((address_space(3))) unsigned int*)l, 16, 0, 0);
}
__device__ __forceinline__ unsigned lds_addr(const void* p) {
  return (unsigned)(unsigned long long)(const __attribute__((address_space(3))) char*)p;
}

#define DSR(dst, off) asm volatile("ds_read_b128 %0, %1" : "=v"(dst) : "v"(off))
#define LGKM0 asm volatile("s_waitcnt lgkmcnt(0)" ::: "memory")
#define VMC0  asm volatile("s_waitcnt vmcnt(0)" ::: "memory")
#define SBAR  __builtin_amdgcn_s_barrier()
#define SCH0  __builtin_amdgcn_sched_barrier(0)

// ---------------- f32 -> bf16 convert (hw cvt), 16 elems/thread -------
__global__ __launch_bounds__(256) void k_cvt3(
    const float* __restrict__ q, const float* __restrict__ k, const float* __restrict__ v,
    unsigned short* __restrict__ qo, unsigned short* __restrict__ ko, unsigned short* __restrict__ vo) {
  const float* in = (blockIdx.y == 0) ? q : (blockIdx.y == 1) ? k : v;
  unsigned short* out = (blockIdx.y == 0) ? qo : (blockIdx.y == 1) ? ko : vo;
  size_t i = ((size_t)blockIdx.x * 256 + threadIdx.x) * 16;
  const float4* p = (const float4*)(in + i);
  float4 a = p[0], b = p[1], c = p[2], d = p[3];
  u16x8 o0, o1;
  o0[0] = f2bfh(a.x); o0[1] = f2bfh(a.y); o0[2] = f2bfh(a.z); o0[3] = f2bfh(a.w);
  o0[4] = f2bfh(b.x); o0[5] = f2bfh(b.y); o0[6] = f2bfh(b.z); o0[7] = f2bfh(b.w);
  o1[0] = f2bfh(c.x); o1[1] = f2bfh(c.y); o1[2] = f2bfh(c.z); o1[3] = f2bfh(c.w);
  o1[4] = f2bfh(d.x); o1[5] = f2bfh(d.y); o1[6] = f2bfh(d.z); o1[7] = f2bfh(d.w);
  *(u16x8*)(out + i) = o0;
  *(u16x8*)(out + i + 8) = o1;
}

// ---------------- W (1024x1024 f32) -> W^T bf16, 3 weights ------------
__global__ __launch_bounds__(256) void k_cvt_w3(
    const float* __restrict__ Wq, const float* __restrict__ Wk, const float* __restrict__ Wv,
    unsigned short* __restrict__ Tq, unsigned short* __restrict__ Tk, unsigned short* __restrict__ Tv) {
  const float* W = (blockIdx.z == 0) ? Wq : (blockIdx.z == 1) ? Wk : Wv;
  unsigned short* WT = (blockIdx.z == 0) ? Tq : (blockIdx.z == 1) ? Tk : Tv;
  __shared__ float t[32][33];
  const int tid = threadIdx.x;
  const int tx = tid & 31, ty = tid >> 5;
  const int e0 = blockIdx.y * 32, a0 = blockIdx.x * 32;
#pragma unroll
  for (int i = 0; i < 4; i++) {
    int el = ty + i * 8;
    t[el][tx] = W[(size_t)(e0 + el) * 1024 + a0 + tx];
  }
  __syncthreads();
#pragma unroll
  for (int i = 0; i < 4; i++) {
    int al = ty + i * 8;
    WT[(size_t)(a0 + al) * 1024 + e0 + tx] = f2bf(t[tx][al]);
  }
}

// ---------------- mask int32 -> bits, 16 ints per thread --------------
__global__ __launch_bounds__(256) void k_maskbits(const int* __restrict__ mask,
                                                  unsigned short* __restrict__ bits) {
  size_t t = (size_t)blockIdx.x * 256 + threadIdx.x;
  const int4* p = (const int4*)(mask + t * 16);
  int4 a = p[0], b = p[1], c = p[2], d = p[3];
  unsigned m = 0;
  m |= (a.x != 0) ? 1u : 0u;      m |= (a.y != 0) ? 2u : 0u;
  m |= (a.z != 0) ? 4u : 0u;      m |= (a.w != 0) ? 8u : 0u;
  m |= (b.x != 0) ? 16u : 0u;     m |= (b.y != 0) ? 32u : 0u;
  m |= (b.z != 0) ? 64u : 0u;     m |= (b.w != 0) ? 128u : 0u;
  m |= (c.x != 0) ? 256u : 0u;    m |= (c.y != 0) ? 512u : 0u;
  m |= (c.z != 0) ? 1024u : 0u;   m |= (c.w != 0) ? 2048u : 0u;
  m |= (d.x != 0) ? 4096u : 0u;   m |= (d.y != 0) ? 8192u : 0u;
  m |= (d.z != 0) ? 16384u : 0u;  m |= (d.w != 0) ? 32768u : 0u;
  bits[t] = (unsigned short)m;
}

// ------- zero the 64 diagonal-adjacent E tiles PV reads but scores
// ------- never writes: rows [256R,256R+128), cols [256R+128,256R+256)
__global__ __launch_bounds__(256) void k_zdiag(unsigned short* __restrict__ E) {
  const int R = blockIdx.x, b = blockIdx.y;
  unsigned short* base = E + (size_t)b * 2048 * 2048
                           + (size_t)(R * 256) * 2048 + (R * 256 + 128);
  const u16x8 z = {0, 0, 0, 0, 0, 0, 0, 0};
  for (int i = threadIdx.x; i < 2048; i += 256) {
    int row = i >> 4, c = (i & 15) * 8;
    *(u16x8*)(base + (size_t)row * 2048 + c) = z;
  }
}

// =====================================================================
// 256x256 2-phase core (8 waves 2x4, BK=64, gl16 both sides) — proj/pv.
// =====================================================================
__device__ __forceinline__ void gemm256_core(
    const unsigned short* __restrict__ A, int lda,
    const unsigned short* __restrict__ Bt, int ldb,
    int brow, int bcol, int NT,
    unsigned short* As0, unsigned short* Bs0,
    f32x4 (&acc)[8][4])
{
  const int tid = threadIdx.x, w = tid >> 6, l = tid & 63;
  const int wr = w >> 2, wc = w & 3;
  const int fr = l & 15, fq = l >> 4;
  const int hr = l >> 3;
  const int hc = ((l & 7) ^ hr) * 8;

  const unsigned short* ga = A + (size_t)(brow + w * 32 + hr) * lda + hc;
  const unsigned short* gb = Bt + (size_t)(bcol + w * 32 + hr) * ldb + hc;

  unsigned aA[8], aB[4];
#pragma unroll
  for (int m = 0; m < 8; m++) aA[m] = lds_addr(As0) + (unsigned)((wr * 128 + m * 16 + fr) * 128);
#pragma unroll
  for (int n = 0; n < 4; n++) aB[n] = lds_addr(Bs0) + (unsigned)((wc * 64 + n * 16 + fr) * 128);
  const unsigned ck0 = (unsigned)((fq ^ (fr & 7)) * 16);
  const unsigned ck1 = (unsigned)(((4 + fq) ^ (fr & 7)) * 16);

  auto stage = [&](int buf, int k0) {
#pragma unroll
    for (int i = 0; i < 4; i++) {
      gl16(ga + (size_t)(8 * i) * lda + k0, As0 + buf * (256 * 64) + (w * 32 + 8 * i) * 64);
      gl16(gb + (size_t)(8 * i) * ldb + k0, Bs0 + buf * (256 * 64) + (w * 32 + 8 * i) * 64);
    }
  };

  stage(0, 0);
  VMC0; SBAR;
  for (int t = 0; t < NT; ++t) {
    if (t + 1 < NT) stage((t + 1) & 1, (t + 1) << 6);
    const unsigned bo = (unsigned)((t & 1) * (256 * 64 * 2));
    u16x8 ar[8], br[4];
#pragma unroll
    for (int m = 0; m < 8; m++) DSR(ar[m], aA[m] + bo + ck0);
#pragma unroll
    for (int n = 0; n < 4; n++) DSR(br[n], aB[n] + bo + ck0);
    LGKM0; SCH0;
    __builtin_amdgcn_s_setprio(1);
#pragma unroll
    for (int m = 0; m < 8; m++)
#pragma unroll
      for (int n = 0; n < 4; n++)
        acc[m][n] = __builtin_amdgcn_mfma_f32_16x16x32_bf16(
            __builtin_bit_cast(bf16x8, ar[m]), __builtin_bit_cast(bf16x8, br[n]), acc[m][n], 0, 0, 0);
    __builtin_amdgcn_s_setprio(0);
    u16x8 ar2[8], br2[4];
#pragma unroll
    for (int m = 0; m < 8; m++) DSR(ar2[m], aA[m] + bo + ck1);
#pragma unroll
    for (int n = 0; n < 4; n++) DSR(br2[n], aB[n] + bo + ck1);
    LGKM0; SCH0;
    __builtin_amdgcn_s_setprio(1);
#pragma unroll
    for (int m = 0; m < 8; m++)
#pragma unroll
      for (int n = 0; n < 4; n++)
        acc[m][n] = __builtin_amdgcn_mfma_f32_16x16x32_bf16(
            __builtin_bit_cast(bf16x8, ar2[m]), __builtin_bit_cast(bf16x8, br2[n]), acc[m][n], 0, 0, 0);
    __builtin_amdgcn_s_setprio(0);
    SCH0;
    VMC0; SBAR;
  }
}

// ---------------- projections (256^2) ----------------
__global__ __launch_bounds__(512, 2) void k_proj256(
    const unsigned short* __restrict__ A, int lda,
    const unsigned short* __restrict__ Bt, int ldb,
    unsigned short* __restrict__ C, int ldc, float scale)
{
  const int nwg = gridDim.x * gridDim.y;
  int lin = blockIdx.y * gridDim.x + blockIdx.x;
  int swz = (lin & 7) * (nwg >> 3) + (lin >> 3);
  const int bx = swz % gridDim.x, by = swz / gridDim.x;
  const int brow = by * 256, bcol = bx * 256;

  __shared__ unsigned short As[2][256 * 64];
  __shared__ unsigned short Bs[2][256 * 64];
  const int tid = threadIdx.x, w = tid >> 6, l = tid & 63;
  const int wr = w >> 2, wc = w & 3;
  const int fr = l & 15, fq = l >> 4;

  f32x4 acc[8][4] = {};
  gemm256_core(A, lda, Bt, ldb, brow, bcol, 16, &As[0][0], &Bs[0][0], acc);

#pragma unroll
  for (int m = 0; m < 8; m++)
#pragma unroll
    for (int n = 0; n < 4; n++)
#pragma unroll
      for (int r = 0; r < 4; r++) {
        int rg = brow + wr * 128 + m * 16 + fq * 4 + r;
        int cg = bcol + wc * 64 + n * 16 + fr;
        C[(size_t)rg * ldc + cg] = f2bf(acc[m][n][r] * scale);
      }
}

// =====================================================================
// 128x128 2-phase core (4 waves, BK=64, 64 KiB LDS, 2 blocks/CU) — scores
// =====================================================================
__device__ __forceinline__ void tile128_gemm(
    const unsigned short* __restrict__ A, int lda,
    const unsigned short* __restrict__ Bt, int ldb,
    int brow, int bcol, int NT,
    unsigned short* AsBase, unsigned short* BsBase,
    int wr, int wc, int fr, int fq,
    f32x4 (&acc)[4][4])
{
  const int tid = threadIdx.x, wid = tid >> 6, l = tid & 63;
  const int sr = l >> 3;
  const int sc = ((l & 7) ^ sr) * 8;

  const unsigned short* ga = A + (size_t)(brow + wid * 32 + sr) * lda + sc;
  const unsigned short* gb = Bt + (size_t)(bcol + wid * 32 + sr) * ldb + sc;

  unsigned aA[4], aB[4];
#pragma unroll
  for (int m = 0; m < 4; m++) aA[m] = lds_addr(AsBase) + (unsigned)((wr * 64 + m * 16 + fr) * 128);
#pragma unroll
  for (int n = 0; n < 4; n++) aB[n] = lds_addr(BsBase) + (unsigned)((wc * 64 + n * 16 + fr) * 128);
  const unsigned ck0 = (unsigned)((fq ^ (fr & 7)) * 16);
  const unsigned ck1 = (unsigned)(((4 + fq) ^ (fr & 7)) * 16);

  auto stage = [&](int buf, int k0) {
    unsigned short* la = AsBase + buf * (128 * 64);
    unsigned short* lb = BsBase + buf * (128 * 64);
#pragma unroll
    for (int i = 0; i < 4; i++) {
      gl16(ga + (size_t)(8 * i) * lda + k0, la + (wid * 32 + 8 * i) * 64);
      gl16(gb + (size_t)(8 * i) * ldb + k0, lb + (wid * 32 + 8 * i) * 64);
    }
  };

  stage(0, 0);
  VMC0; SBAR;

  for (int t = 0; t < NT; ++t) {
    if (t + 1 < NT) stage((t + 1) & 1, (t + 1) << 6);
    const unsigned bo = (unsigned)((t & 1) * (128 * 64 * 2));
    u16x8 ar[4], br[4];
#pragma unroll
    for (int m = 0; m < 4; m++) DSR(ar[m], aA[m] + bo + ck0);
#pragma unroll
    for (int n = 0; n < 4; n++) DSR(br[n], aB[n] + bo + ck0);
    LGKM0; SCH0;
    __builtin_amdgcn_s_setprio(1);
#pragma unroll
    for (int m = 0; m < 4; m++)
#pragma unroll
      for (int n = 0; n < 4; n++)
        acc[m][n] = __builtin_amdgcn_mfma_f32_16x16x32_bf16(
            __builtin_bit_cast(bf16x8, ar[m]), __builtin_bit_cast(bf16x8, br[n]), acc[m][n], 0, 0, 0);
    __builtin_amdgcn_s_setprio(0);
    u16x8 ar2[4], br2[4];
#pragma unroll
    for (int m = 0; m < 4; m++) DSR(ar2[m], aA[m] + bo + ck1);
#pragma unroll
    for (int n = 0; n < 4; n++) DSR(br2[n], aB[n] + bo + ck1);
    LGKM0; SCH0;
    __builtin_amdgcn_s_setprio(1);
#pragma unroll
    for (int m = 0; m < 4; m++)
#pragma unroll
      for (int n = 0; n < 4; n++)
        acc[m][n] = __builtin_amdgcn_mfma_f32_16x16x32_bf16(
            __builtin_bit_cast(bf16x8, ar2[m]), __builtin_bit_cast(bf16x8, br2[n]), acc[m][n], 0, 0, 0);
    __builtin_amdgcn_s_setprio(0);
    SCH0;
    VMC0;
    SBAR;
  }
}

// -------- scores: 128-tile causal grid, exp fused, atomic row sums ----
__global__ __launch_bounds__(256, 2) void k_scores(
    const unsigned short* __restrict__ QP,
    const unsigned short* __restrict__ KP,
    unsigned short* __restrict__ E,      // exp(S) bf16
    const unsigned short* __restrict__ maskbits,
    float* __restrict__ rowsum)
{
  int bid0 = blockIdx.x;
  int bid = (bid0 & 7) * 136 + (bid0 >> 3);   // 1088 % 8 == 0: bijective
  const int b = bid / 136;
  int t0 = bid - b * 136;
  int by = (int)((sqrtf((float)(8 * t0 + 1)) - 1.0f) * 0.5f);
  if ((by + 1) * (by + 2) / 2 <= t0) by++;
  else if (by * (by + 1) / 2 > t0) by--;
  const int bx = t0 - (by * (by + 1)) / 2;     // bx <= by
  const int brow = by * 128, bcol = bx * 128;

  const unsigned short* A  = QP + (size_t)b * (2048 * 1024);
  const unsigned short* Bt = KP + (size_t)b * (2048 * 1024);

  __shared__ unsigned short As[2][128 * 64];
  __shared__ unsigned short Bs[2][128 * 64];

  const int tid = threadIdx.x, wid = tid >> 6, lane = tid & 63;
  const int wr = wid >> 1, wc = wid & 1;
  const int fr = lane & 15, fq = lane >> 4;

  const unsigned short* bits = maskbits + (size_t)b * 2048 * 128;
  unsigned mbits[2] = {0u, 0u};
#pragma unroll
  for (int m = 0; m < 4; m++)
#pragma unroll
    for (int r = 0; r < 4; r++) {
      int qq = brow + wr * 64 + m * 16 + fq * 4 + r;
      unsigned long long mw =
          *(const unsigned long long*)(bits + (size_t)qq * 128 + ((bcol + wc * 64) >> 4));
#pragma unroll
      for (int n = 0; n < 4; n++) {
        int jj = (m << 4) | (n << 2) | r;
        unsigned bit = (unsigned)((mw >> (n * 16 + fr)) & 1ull);
        mbits[jj >> 5] |= bit << (jj & 31);
      }
    }
  asm volatile("" ::: "memory");

  f32x4 acc[4][4] = {};
  tile128_gemm(A, 1024, Bt, 1024, brow, bcol, 16, &As[0][0], &Bs[0][0],
               wr, wc, fr, fq, acc);

  // epilogue: e = exp(s) with quirks; store bf16; reduce row sums
  unsigned short* Cb = E + (size_t)b * 2048 * 2048;
  float* rs = rowsum + (size_t)b * 2048;
#pragma unroll
  for (int m = 0; m < 4; m++)
#pragma unroll
    for (int r = 0; r < 4; r++) {
      int qq = brow + wr * 64 + m * 16 + fq * 4 + r;
      float se = 0.f;
#pragma unroll
      for (int n = 0; n < 4; n++) {
        int jj = (m << 4) | (n << 2) | r;
        int kk = bcol + wc * 64 + n * 16 + fr;
        float s = acc[m][n][r];
        bool dead = !((mbits[jj >> 5] >> (jj & 31)) & 1u) || (kk > qq) || (s == 0.0f);
        float e = dead ? 0.f : __expf(s);
        se += e;
        Cb[(size_t)qq * 2048 + kk] = f2bf(e);
      }
      // reduce across the 16-lane fr group (lanes fq*16 + 0..15)
      se += __shfl_xor(se, 1);
      se += __shfl_xor(se, 2);
      se += __shfl_xor(se, 4);
      se += __shfl_xor(se, 8);
      if (fr == 0) atomicAdd(&rs[qq], se);
    }
}

// ---------- PV (256^2): out = E x vpT^T scaled by 1/rowsum ------------
__global__ __launch_bounds__(512, 2) void k_pv256(
    const unsigned short* __restrict__ E,
    const unsigned short* __restrict__ VpT,
    const float* __restrict__ rowsum,
    float* __restrict__ Out)
{
  const int b = blockIdx.z;
  const int by = (int)(gridDim.y - 1 - blockIdx.y);   // long K first
  const int bx = blockIdx.x;
  const int brow = by * 256, bcol = bx * 256;

  const unsigned short* A  = E + (size_t)b * 2048 * 2048;
  const unsigned short* Bt = VpT + (size_t)b * 2048;

  __shared__ unsigned short As[2][256 * 64];
  __shared__ unsigned short Bs[2][256 * 64];
  const int tid = threadIdx.x, w = tid >> 6, l = tid & 63;
  const int wr = w >> 2, wc = w & 3;
  const int fr = l & 15, fq = l >> 4;

  f32x4 acc[8][4] = {};
  const int NT = (brow + 256) >> 6;
  gemm256_core(A, 2048, Bt, 16384, brow, bcol, NT, &As[0][0], &Bs[0][0], acc);

  const float* rs = rowsum + (size_t)b * 2048;
  float* C = Out + (size_t)b * 2048 * 1024;
#pragma unroll
  for (int m = 0; m < 8; m++)
#pragma unroll
    for (int r = 0; r < 4; r++) {
      int rg = brow + wr * 128 + m * 16 + fq * 4 + r;
      float inv = 1.0f / rs[rg];
#pragma unroll
      for (int n = 0; n < 4; n++) {
        int cg = bcol + wc * 64 + n * 16 + fr;
        C[(size_t)rg * 1024 + cg] = acc[m][n][r] * inv;
      }
    }
}

extern "C" void kernel_launch(void* const* d_in, const int* in_sizes, int n_in,
                              void* d_out, int out_size, void* d_ws, size_t ws_size,
                              hipStream_t stream) {
  const float* q   = (const float*)d_in[0];
  const float* k   = (const float*)d_in[1];
  const float* v   = (const float*)d_in[2];
  const int*   msk = (const int*)d_in[3];
  const float* Wq  = (const float*)d_in[4];
  const float* Wk  = (const float*)d_in[5];
  const float* Wv  = (const float*)d_in[6];
  float* out = (float*)d_out;

  char* ws = (char*)d_ws;
  unsigned short* WqT = (unsigned short*)(ws + 0);
  unsigned short* WkT = (unsigned short*)(ws + 2097152);
  unsigned short* WvT = (unsigned short*)(ws + 4194304);
  unsigned short* qp  = (unsigned short*)(ws + 6291456);
  unsigned short* kp  = (unsigned short*)(ws + 39845888);
  unsigned short* vpT = (unsigned short*)(ws + 73400320);
  unsigned short* qbf = (unsigned short*)(ws + 106954752);
  unsigned short* kbf = (unsigned short*)(ws + 140509184);
  unsigned short* vbf = (unsigned short*)(ws + 174063616);
  // E (exp(S) bf16, 67 MB) aliases qbf/kbf (dead after projections)
  unsigned short* E = (unsigned short*)(ws + 106954752);
  unsigned short* mbitsbuf = (unsigned short*)(ws + 207618048);  // 4 MiB
  float* rowsum = (float*)(ws + 211812352);                       // 64 KiB

  dim3 blk(256), blk5(512);
  // 1) conversions + mask packing + rowsum zero
  k_cvt3<<<dim3(4096, 3), blk, 0, stream>>>(q, k, v, qbf, kbf, vbf);
  k_cvt_w3<<<dim3(32, 32, 3), blk, 0, stream>>>(Wq, Wk, Wv, WqT, WkT, WvT);
  k_maskbits<<<dim3(8192), blk, 0, stream>>>(msk, mbitsbuf);
  hipMemsetAsync(rowsum, 0, 16384 * sizeof(float), stream);

  // 2) projections (256^2 2-phase): qp (1/32 folded), kp, vpT
  k_proj256<<<dim3(4, 64), blk5, 0, stream>>>(qbf, 1024, WqT, 1024, qp, 1024, 0.03125f);
  k_proj256<<<dim3(4, 64), blk5, 0, stream>>>(kbf, 1024, WkT, 1024, kp, 1024, 1.0f);
  k_proj256<<<dim3(64, 4), blk5, 0, stream>>>(WvT, 1024, vbf, 1024, vpT, 16384, 1.0f);

  // 2b) zero the diagonal-adjacent E tiles PV reads but scores skips
  //     (must be after projections: E aliases qbf/kbf)
  k_zdiag<<<dim3(8, 8), blk, 0, stream>>>(E);

  // 3) scores: E = exp(masked S), rowsum accumulated atomically
  k_scores<<<dim3(1088), blk, 0, stream>>>(qp, kp, E, mbitsbuf, rowsum);

  // 4) PV with output normalization (no separate softmax pass)
  k_pv256<<<dim3(4, 8, 8), blk5, 0, stream>>>(E, vpT, rowsum, out);
  (void)in_sizes; (void)n_in; (void)out_size; (void)ws_size;
}